// Round 10
// baseline (324.838 us; speedup 1.0000x reference)
//
#include <hip/hip_runtime.h>
#include <math.h>

// Problem constants (from reference)
#define N1C 40000
#define N2C 10000
#define DIN 128
#define DH  256
#define NC  47

#define TOTCNT (2 * N1C + 2 * N2C)          // 100000 concatenated bins
#define CAP 64                              // merged-bucket capacity per bin
#define NREP 8                              // XCD-sharded replicas (blockIdx&7)
#define CAPR 16                             // per-replica capacity: P[Pois(1.9)>=17]~2e-11

typedef __attribute__((ext_vector_type(8))) short v8s;
typedef __attribute__((ext_vector_type(4))) float v4f;
typedef __attribute__((ext_vector_type(2))) float v2f;

#if __has_builtin(__builtin_amdgcn_cvt_pk_f32_fp8)
#define HW_FP8 1
#endif

__device__ __forceinline__ unsigned short f2bf(float f) {
    unsigned int u = __float_as_uint(f);
    u += 0x7FFF + ((u >> 16) & 1);            // round-to-nearest-even
    return (unsigned short)(u >> 16);
}

// ---- manual OCP e4m3fn encode (RNE, saturating) — fallback only ----
__device__ __forceinline__ unsigned char f2e4m3(float f) {
    unsigned int u = __float_as_uint(f);
    unsigned char s = (unsigned char)((u >> 24) & 0x80);
    float a = __uint_as_float(u & 0x7FFFFFFF);
    if (a > 448.0f) a = 448.0f;
    if (a < 0.015625f) {                       // subnorm / zero: quantum 2^-9
        int k = (int)rintf(a * 512.0f);        // 0..8 (8 rolls into e=1,m=0)
        return s | (unsigned char)k;
    }
    unsigned int bits = __float_as_uint(a);
    int et = (int)(bits >> 23) - 127 + 7;      // target exponent 1..15
    unsigned int m32 = bits & 0x7FFFFF;
    unsigned int m3 = m32 >> 20;
    unsigned int rest = m32 & 0xFFFFF;
    if (rest > 0x80000 || (rest == 0x80000 && (m3 & 1))) m3++;
    if (m3 == 8) { m3 = 0; et++; }
    if (et > 15 || (et == 15 && m3 == 7)) return s | 0x7E;   // clamp to 448
    return s | (unsigned char)((et << 3) | m3);
}

// pack 4 floats -> 4 e4m3 bytes (HW converter: r5/r6-verified)
__device__ __forceinline__ unsigned int pack4_e4m3(float f0, float f1,
                                                   float f2, float f3) {
#if __has_builtin(__builtin_amdgcn_cvt_pk_fp8_f32)
    int q = __builtin_amdgcn_cvt_pk_fp8_f32(f0, f1, 0, false);
    q = __builtin_amdgcn_cvt_pk_fp8_f32(f2, f3, q, true);
    return (unsigned int)q;
#else
    return (unsigned int)f2e4m3(f0) | ((unsigned int)f2e4m3(f1) << 8) |
           ((unsigned int)f2e4m3(f2) << 16) | ((unsigned int)f2e4m3(f3) << 24);
#endif
}

// decode 4 packed e4m3 bytes -> 4 floats
__device__ __forceinline__ void dec4(unsigned int u, float& f0, float& f1,
                                     float& f2, float& f3) {
#ifdef HW_FP8
    v2f lo = __builtin_amdgcn_cvt_pk_f32_fp8((int)u, false);
    v2f hi = __builtin_amdgcn_cvt_pk_f32_fp8((int)u, true);
    f0 = lo[0]; f1 = lo[1]; f2 = hi[0]; f3 = hi[1];
#else
    auto d1 = [](unsigned int b) -> float {
        int e = (b >> 3) & 15, mm = b & 7;
        float d = (e == 0) ? (float)mm * (1.0f / 512.0f)
                           : (1.0f + (float)mm * 0.125f) * exp2f((float)(e - 7));
        return (b & 0x80) ? -d : d;
    };
    f0 = d1(u & 0xFF); f1 = d1((u >> 8) & 0xFF);
    f2 = d1((u >> 16) & 0xFF); f3 = d1(u >> 24);
#endif
}

// accumulate 16 fp8 (one uint4) into 16 float accumulators
__device__ __forceinline__ void acc16(uint4 q, float* a) {
    float f0, f1, f2, f3;
    dec4(q.x, f0, f1, f2, f3); a[0] += f0; a[1] += f1; a[2] += f2; a[3] += f3;
    dec4(q.y, f0, f1, f2, f3); a[4] += f0; a[5] += f1; a[6] += f2; a[7] += f3;
    dec4(q.z, f0, f1, f2, f3); a[8] += f0; a[9] += f1; a[10] += f2; a[11] += f3;
    dec4(q.w, f0, f1, f2, f3); a[12] += f0; a[13] += f1; a[14] += f2; a[15] += f3;
}

// ====== fused front-end: thread-level {fill + conv} | weights in tail =============
// XCD-sharded fill: replica r = blockIdx&7 owns its own counters + bucket slots,
// so counter/scatter lines are touched by ~one XCD -> local-L2 atomics, no fabric
// line ping-pong (theory: that migration is the 60us fill cost).
__global__ __launch_bounds__(256) void front_fused(
        const int* __restrict__ src0, const int* __restrict__ dst0,
        const int* __restrict__ srcb0, const int* __restrict__ dstb0,
        const int* __restrict__ src1, const int* __restrict__ dst1,
        const int* __restrict__ srcb1, const int* __restrict__ dstb1,
        const int* __restrict__ perm, int* __restrict__ cur,
        int* __restrict__ bucket, int E0, int E1, int nbMain,
        const float* __restrict__ x0, unsigned char* __restrict__ x0f,
        int n8,
        const float* __restrict__ Wl0, const float* __restrict__ Wr0,
        const float* __restrict__ Wl1, const float* __restrict__ Wr1,
        unsigned short* __restrict__ Wt0l, unsigned short* __restrict__ Wt0r,
        unsigned short* __restrict__ Wt1l, unsigned short* __restrict__ Wt1r) {
    int b = blockIdx.x, t = threadIdx.x;
    if (b < nbMain) {
        int gid = b * 256 + t;
        int rep = b & (NREP - 1);
        // ---- fill: compute bin + issue atomic early ----
        int tot = 2 * E0 + 2 * E1;
        bool doEdge = gid < tot;
        int s = 0, bin = 0, pos = CAPR;
        if (doEdge) {
            if (gid < E0) {
                s = src0[gid];                bin = dst0[gid];
            } else if (gid < 2 * E0) {
                int le = gid - E0;
                s = perm[srcb0[le]];          bin = N1C + dstb0[le];
            } else if (gid < 2 * E0 + E1) {
                int le = gid - 2 * E0;
                s = src1[le];                 bin = 2 * N1C + dst1[le];
            } else {
                int le = gid - 2 * E0 - E1;
                s = perm[srcb1[le]];          bin = 2 * N1C + N2C + dstb1[le];
            }
            pos = atomicAdd(&cur[(size_t)rep * TOTCNT + bin], 1);
        }
        // ---- conv: x0 -> fp8 (8 elems), overlaps the atomic round-trip ----
        if (gid < n8) {
            const float4* p = (const float4*)(x0 + (size_t)gid * 8);
            float4 a = p[0], c = p[1];
            uint2 q;
            q.x = pack4_e4m3(a.x, a.y, a.z, a.w);
            q.y = pack4_e4m3(c.x, c.y, c.z, c.w);
            *(uint2*)(x0f + (size_t)gid * 8) = q;
        }
        // ---- dependent scatter last (replica-local line) ----
        if (doEdge && pos < CAPR)
            bucket[((size_t)rep * TOTCNT + bin) * CAPR + pos] = s;
    } else {
        // ---- weight transpose + bf16: Wt[n][k] = W[k][n] ----
        int id = (b - nbMain) * 256 + t;
        const int S0 = DIN * DH;   // 32768
        const int S1 = DH * DH;    // 65536
        const float* W; unsigned short* Wt; int K, loc;
        if (id < S0)                   { W = Wl0; Wt = Wt0l; K = DIN; loc = id; }
        else if (id < 2 * S0)          { W = Wr0; Wt = Wt0r; K = DIN; loc = id - S0; }
        else if (id < 2 * S0 + S1)     { W = Wl1; Wt = Wt1l; K = DH;  loc = id - 2 * S0; }
        else if (id < 2 * S0 + 2 * S1) { W = Wr1; Wt = Wt1r; K = DH;  loc = id - 2 * S0 - S1; }
        else return;
        int n = loc / K, k = loc - n * K;
        Wt[(size_t)n * K + k] = f2bf(W[(size_t)k * DH + n]);
    }
}

// ====== gather-mean D=128: LDS-merge 8 replica lists, then 16B/lane unroll-4 ======
__global__ __launch_bounds__(256) void gather_mean_128f(
        const unsigned char* __restrict__ xf, const int* __restrict__ bucket,
        const int* __restrict__ cur, unsigned short* __restrict__ mean0,
        unsigned short* __restrict__ meanb0) {
    const int half = N1C / 32;                 // 1250 blocks per branch
    int b = blockIdx.x;
    int binbase; unsigned short* outp; int rb;
    if (b < half) { binbase = 0;   outp = mean0;  rb = b; }
    else          { binbase = N1C; outp = meanb0; rb = b - half; }
    int t = threadIdx.x;
    __shared__ int midx[32][NREP * CAPR];      // merged index lists (16KB)
    __shared__ int mcnt[32];
    {   // merge: 8 threads per row, one replica each; prefix over replica counts
        int rloc = t >> 3, rep = t & 7;
        int bin = binbase + rb * 32 + rloc;
        int off = 0, cr = 0;
        for (int j = 0; j <= rep; j++) {
            int c = min(cur[(size_t)j * TOTCNT + bin], CAPR);
            if (j < rep) off += c; else cr = c;
        }
        const int* bp = &bucket[((size_t)rep * TOTCNT + bin) * CAPR];
        for (int k = 0; k < cr; k++) midx[rloc][off + k] = bp[k];
        if (rep == 7) mcnt[rloc] = off + cr;
    }
    __syncthreads();
    int rloc = t >> 3;
    int row = rb * 32 + rloc;                  // 32 rows/block
    int c16 = (t & 7) * 16;                    // byte offset within 128B row
    int cnt = mcnt[rloc];
    const int* cs = &midx[rloc][0];
    float a[16];
#pragma unroll
    for (int j = 0; j < 16; j++) a[j] = 0.0f;
    int i = 0;
    for (; i + 3 < cnt; i += 4) {
        int s0 = cs[i], s1 = cs[i + 1], s2 = cs[i + 2], s3 = cs[i + 3];
        uint4 q0 = *(const uint4*)&xf[(size_t)s0 * DIN + c16];
        uint4 q1 = *(const uint4*)&xf[(size_t)s1 * DIN + c16];
        uint4 q2 = *(const uint4*)&xf[(size_t)s2 * DIN + c16];
        uint4 q3 = *(const uint4*)&xf[(size_t)s3 * DIN + c16];
        acc16(q0, a); acc16(q1, a); acc16(q2, a); acc16(q3, a);
    }
    for (; i < cnt; i++) {
        uint4 q = *(const uint4*)&xf[(size_t)cs[i] * DIN + c16];
        acc16(q, a);
    }
    float inv = 1.0f / (float)max(cnt, 1);
    uint4 o0, o1;
    o0.x = (unsigned int)f2bf(a[0] * inv)  | ((unsigned int)f2bf(a[1] * inv) << 16);
    o0.y = (unsigned int)f2bf(a[2] * inv)  | ((unsigned int)f2bf(a[3] * inv) << 16);
    o0.z = (unsigned int)f2bf(a[4] * inv)  | ((unsigned int)f2bf(a[5] * inv) << 16);
    o0.w = (unsigned int)f2bf(a[6] * inv)  | ((unsigned int)f2bf(a[7] * inv) << 16);
    o1.x = (unsigned int)f2bf(a[8] * inv)  | ((unsigned int)f2bf(a[9] * inv) << 16);
    o1.y = (unsigned int)f2bf(a[10] * inv) | ((unsigned int)f2bf(a[11] * inv) << 16);
    o1.z = (unsigned int)f2bf(a[12] * inv) | ((unsigned int)f2bf(a[13] * inv) << 16);
    o1.w = (unsigned int)f2bf(a[14] * inv) | ((unsigned int)f2bf(a[15] * inv) << 16);
    unsigned short* op = &outp[(size_t)row * DIN + c16];
    *(uint4*)op = o0;
    *(uint4*)(op + 8) = o1;
}

// ====== gather-mean D=256: LDS-merge + 16B/lane, 4 rows/wave ======================
__global__ __launch_bounds__(256) void gather_mean_256f(
        const unsigned char* __restrict__ xf, const int* __restrict__ bucket,
        const int* __restrict__ cur, unsigned short* __restrict__ mean1,
        unsigned short* __restrict__ meanb1) {
    const int half = N2C / 16;                 // 625 blocks per branch
    int b = blockIdx.x;
    int binbase; unsigned short* outp; int rb;
    if (b < half) { binbase = 2 * N1C;       outp = mean1;  rb = b; }
    else          { binbase = 2 * N1C + N2C; outp = meanb1; rb = b - half; }
    int t = threadIdx.x;
    __shared__ int midx[16][NREP * CAPR];      // 8KB
    __shared__ int mcnt[16];
    {   // merge: first 8 of each 16-thread row-group handle one replica each
        int rloc = t >> 4, sub = t & 15;
        if (sub < 8) {
            int rep = sub;
            int bin = binbase + rb * 16 + rloc;
            int off = 0, cr = 0;
            for (int j = 0; j <= rep; j++) {
                int c = min(cur[(size_t)j * TOTCNT + bin], CAPR);
                if (j < rep) off += c; else cr = c;
            }
            const int* bp = &bucket[((size_t)rep * TOTCNT + bin) * CAPR];
            for (int k = 0; k < cr; k++) midx[rloc][off + k] = bp[k];
            if (rep == 7) mcnt[rloc] = off + cr;
        }
    }
    __syncthreads();
    int rloc = t >> 4;
    int row = rb * 16 + rloc;                  // 16 rows/block
    int c16 = (t & 15) * 16;                   // byte offset within 256B row
    int cnt = mcnt[rloc];
    const int* cs = &midx[rloc][0];
    float a[16];
#pragma unroll
    for (int j = 0; j < 16; j++) a[j] = 0.0f;
    int i = 0;
    for (; i + 3 < cnt; i += 4) {
        int s0 = cs[i], s1 = cs[i + 1], s2 = cs[i + 2], s3 = cs[i + 3];
        uint4 q0 = *(const uint4*)&xf[(size_t)s0 * DH + c16];
        uint4 q1 = *(const uint4*)&xf[(size_t)s1 * DH + c16];
        uint4 q2 = *(const uint4*)&xf[(size_t)s2 * DH + c16];
        uint4 q3 = *(const uint4*)&xf[(size_t)s3 * DH + c16];
        acc16(q0, a); acc16(q1, a); acc16(q2, a); acc16(q3, a);
    }
    for (; i < cnt; i++) {
        uint4 q = *(const uint4*)&xf[(size_t)cs[i] * DH + c16];
        acc16(q, a);
    }
    float inv = 1.0f / (float)max(cnt, 1);
    uint4 o0, o1;
    o0.x = (unsigned int)f2bf(a[0] * inv)  | ((unsigned int)f2bf(a[1] * inv) << 16);
    o0.y = (unsigned int)f2bf(a[2] * inv)  | ((unsigned int)f2bf(a[3] * inv) << 16);
    o0.z = (unsigned int)f2bf(a[4] * inv)  | ((unsigned int)f2bf(a[5] * inv) << 16);
    o0.w = (unsigned int)f2bf(a[6] * inv)  | ((unsigned int)f2bf(a[7] * inv) << 16);
    o1.x = (unsigned int)f2bf(a[8] * inv)  | ((unsigned int)f2bf(a[9] * inv) << 16);
    o1.y = (unsigned int)f2bf(a[10] * inv) | ((unsigned int)f2bf(a[11] * inv) << 16);
    o1.z = (unsigned int)f2bf(a[12] * inv) | ((unsigned int)f2bf(a[13] * inv) << 16);
    o1.w = (unsigned int)f2bf(a[14] * inv) | ((unsigned int)f2bf(a[15] * inv) << 16);
    unsigned short* op = &outp[(size_t)row * DH + c16];
    *(uint4*)op = o0;
    *(uint4*)(op + 8) = o1;
}

// ================= hop-0 MFMA: weights in registers, 5 tiles/block =================
#define KP0 136  // 128 + 8 pad (bf16 units)
#define H0T 5    // grid = 40000/(16*5) = 500
__global__ __launch_bounds__(256, 2) void hop0_mfma(
        const float* __restrict__ x0, const int* __restrict__ idx,
        const unsigned short* __restrict__ mean0, const unsigned short* __restrict__ meanb0,
        const unsigned short* __restrict__ Wtl, const unsigned short* __restrict__ Wtr,
        const float* __restrict__ b, const float* __restrict__ mixp,
        unsigned char* __restrict__ x1f, unsigned short* __restrict__ xm1) {
    __shared__ unsigned short Alds[4][16][KP0];   // 0:mean 1:meanb 2:xr 3:xm
    int t = threadIdx.x;
    int wv = t >> 6, lane = t & 63;
    int mrow = lane & 15, quad = lane >> 4;
    float m = *mixp;

    v8s wl[4][4], wr[4][4];   // [ct][ks]
    float bb[4];
#pragma unroll
    for (int ct = 0; ct < 4; ct++) {
        int n = wv * 64 + mrow * 4 + ct;       // permuted column map
        bb[ct] = b[n];
#pragma unroll
        for (int ks = 0; ks < 4; ks++) {
            int k0 = ks * 32 + quad * 8;
            wl[ct][ks] = *(const v8s*)&Wtl[(size_t)n * DIN + k0];
            wr[ct][ks] = *(const v8s*)&Wtr[(size_t)n * DIN + k0];
        }
    }

    for (int tile = 0; tile < H0T; tile++) {
        int row0 = (blockIdx.x * H0T + tile) * 16;
        {   // stage A: roots read from fp32 x0 directly
            int r = t >> 4, k0 = (t & 15) * 8;
            int rg = row0 + r;
            *(v8s*)&Alds[0][r][k0] = *(const v8s*)&mean0[(size_t)rg * DIN + k0];
            *(v8s*)&Alds[1][r][k0] = *(const v8s*)&meanb0[(size_t)rg * DIN + k0];
            const float4* xr4 = (const float4*)&x0[(size_t)rg * DIN + k0];
            float4 A0 = xr4[0], A1 = xr4[1];
            int ib = idx[rg];
            const float4* xb4 = (const float4*)&x0[(size_t)ib * DIN + k0];
            float4 B0 = xb4[0], B1 = xb4[1];
            float fa[8] = {A0.x, A0.y, A0.z, A0.w, A1.x, A1.y, A1.z, A1.w};
            float fb[8] = {B0.x, B0.y, B0.z, B0.w, B1.x, B1.y, B1.z, B1.w};
            v8s vr, vm;
#pragma unroll
            for (int j = 0; j < 8; j++) {
                vr[j] = (short)f2bf(fa[j]);
                vm[j] = (short)f2bf(m * fa[j] + (1.0f - m) * fb[j]);
            }
            *(v8s*)&Alds[2][r][k0] = vr;
            *(v8s*)&Alds[3][r][k0] = vm;
        }
        __syncthreads();
        v4f accA[4], accB[4], accC[4], accD[4];
#pragma unroll
        for (int ct = 0; ct < 4; ct++) {
            accA[ct] = (v4f){0.f, 0.f, 0.f, 0.f}; accB[ct] = (v4f){0.f, 0.f, 0.f, 0.f};
            accC[ct] = (v4f){0.f, 0.f, 0.f, 0.f}; accD[ct] = (v4f){0.f, 0.f, 0.f, 0.f};
        }
#pragma unroll
        for (int ks = 0; ks < 4; ks++) {
            int k0 = ks * 32 + quad * 8;
            v8s aM = *(v8s*)&Alds[0][mrow][k0];
            v8s aB = *(v8s*)&Alds[1][mrow][k0];
            v8s aR = *(v8s*)&Alds[2][mrow][k0];
            v8s aX = *(v8s*)&Alds[3][mrow][k0];
#pragma unroll
            for (int ct = 0; ct < 4; ct++) {
                accA[ct] = __builtin_amdgcn_mfma_f32_16x16x32_bf16(aM, wl[ct][ks], accA[ct], 0, 0, 0);
                accB[ct] = __builtin_amdgcn_mfma_f32_16x16x32_bf16(aB, wl[ct][ks], accB[ct], 0, 0, 0);
                accC[ct] = __builtin_amdgcn_mfma_f32_16x16x32_bf16(aR, wr[ct][ks], accC[ct], 0, 0, 0);
                accD[ct] = __builtin_amdgcn_mfma_f32_16x16x32_bf16(aX, wr[ct][ks], accD[ct], 0, 0, 0);
            }
        }
        // epilogue: packed coalesced stores (4 consecutive cols per lane)
        int colb = wv * 64 + mrow * 4;
#pragma unroll
        for (int r = 0; r < 4; r++) {
            int row = row0 + quad * 4 + r;
            float xv[4];
            unsigned short sh[4];
#pragma unroll
            for (int ct = 0; ct < 4; ct++) {
                float pA = accA[ct][r], pB = accB[ct][r], pC = accC[ct][r], pD = accD[ct][r];
                xv[ct]    = fmaxf(pA + pC + bb[ct], 0.0f);
                float xn  = fmaxf(pA + pD + bb[ct], 0.0f);
                float xnb = fmaxf(pB + pD + bb[ct], 0.0f);
                sh[ct] = f2bf(m * xn + (1.0f - m) * xnb);
            }
            unsigned int xpack = pack4_e4m3(xv[0], xv[1], xv[2], xv[3]);
            *(unsigned int*)&x1f[(size_t)row * DH + colb] = xpack;
            if (row < N2C) {   // xm1 only consumed for rows < N2C (hop-1 roots)
                unsigned int s01 = (unsigned int)sh[0] | ((unsigned int)sh[1] << 16);
                unsigned int s23 = (unsigned int)sh[2] | ((unsigned int)sh[3] << 16);
                uint2 xm = {s01, s23};
                *(uint2*)&xm1[(size_t)row * DH + colb] = xm;
            }
        }
        __syncthreads();
    }
}

// ================= hop-1 MFMA: half-K weights cached, 2 tiles/block =================
#define KP1 264  // 256 + 8 pad
#define H1T 2
__global__ __launch_bounds__(256, 2) void hop1_mfma(
        const unsigned short* __restrict__ mean1, const unsigned short* __restrict__ meanb1,
        const unsigned short* __restrict__ xm1,
        const unsigned short* __restrict__ Wtl, const unsigned short* __restrict__ Wtr,
        const float* __restrict__ b, const float* __restrict__ mixp,
        float* __restrict__ xm2) {
    __shared__ unsigned short Alds[3][16][KP1];
    int t = threadIdx.x;
    int wv = t >> 6, lane = t & 63;
    int mrow = lane & 15, quad = lane >> 4;
    float m = *mixp;

    v8s wlc[4][4], wrc[4][4];
    float bb[4];
#pragma unroll
    for (int ct = 0; ct < 4; ct++) {
        int n = wv * 64 + mrow * 4 + ct;       // permuted column map
        bb[ct] = b[n];
#pragma unroll
        for (int ks = 0; ks < 4; ks++) {
            int k0 = ks * 32 + quad * 8;
            wlc[ct][ks] = *(const v8s*)&Wtl[(size_t)n * DH + k0];
            wrc[ct][ks] = *(const v8s*)&Wtr[(size_t)n * DH + k0];
        }
    }

    for (int tt = 0; tt < H1T; tt++) {
        int tIdx = blockIdx.x * H1T + tt;
        if (tIdx >= N2C / 16) break;
        int row0 = tIdx * 16;
        {
            int r = t >> 4, k0 = (t & 15) * 16;
            int rg = row0 + r;
            *(v8s*)&Alds[0][r][k0]     = *(const v8s*)&mean1[(size_t)rg * DH + k0];
            *(v8s*)&Alds[0][r][k0 + 8] = *(const v8s*)&mean1[(size_t)rg * DH + k0 + 8];
            *(v8s*)&Alds[1][r][k0]     = *(const v8s*)&meanb1[(size_t)rg * DH + k0];
            *(v8s*)&Alds[1][r][k0 + 8] = *(const v8s*)&meanb1[(size_t)rg * DH + k0 + 8];
            *(v8s*)&Alds[2][r][k0]     = *(const v8s*)&xm1[(size_t)rg * DH + k0];
            *(v8s*)&Alds[2][r][k0 + 8] = *(const v8s*)&xm1[(size_t)rg * DH + k0 + 8];
        }
        __syncthreads();
        v4f accA[4], accB[4], accC[4];
#pragma unroll
        for (int ct = 0; ct < 4; ct++) {
            accA[ct] = (v4f){0.f, 0.f, 0.f, 0.f};
            accB[ct] = (v4f){0.f, 0.f, 0.f, 0.f};
            accC[ct] = (v4f){0.f, 0.f, 0.f, 0.f};
        }
#pragma unroll
        for (int ks = 0; ks < 8; ks++) {
            int k0 = ks * 32 + quad * 8;
            v8s aM = *(v8s*)&Alds[0][mrow][k0];
            v8s aB = *(v8s*)&Alds[1][mrow][k0];
            v8s aR = *(v8s*)&Alds[2][mrow][k0];
#pragma unroll
            for (int ct = 0; ct < 4; ct++) {
                v8s bl, br;
                if (ks < 4) { bl = wlc[ct][ks]; br = wrc[ct][ks]; }
                else {
                    int n = wv * 64 + mrow * 4 + ct;
                    bl = *(const v8s*)&Wtl[(size_t)n * DH + k0];
                    br = *(const v8s*)&Wtr[(size_t)n * DH + k0];
                }
                accA[ct] = __builtin_amdgcn_mfma_f32_16x16x32_bf16(aM, bl, accA[ct], 0, 0, 0);
                accB[ct] = __builtin_amdgcn_mfma_f32_16x16x32_bf16(aB, bl, accB[ct], 0, 0, 0);
                accC[ct] = __builtin_amdgcn_mfma_f32_16x16x32_bf16(aR, br, accC[ct], 0, 0, 0);
            }
        }
        int colb = wv * 64 + mrow * 4;
#pragma unroll
        for (int r = 0; r < 4; r++) {
            int row = row0 + quad * 4 + r;
            float4 o;
            float v0 = fmaxf(accA[0][r] + accC[0][r] + bb[0], 0.0f);
            float w0 = fmaxf(accB[0][r] + accC[0][r] + bb[0], 0.0f);
            float v1 = fmaxf(accA[1][r] + accC[1][r] + bb[1], 0.0f);
            float w1 = fmaxf(accB[1][r] + accC[1][r] + bb[1], 0.0f);
            float v2 = fmaxf(accA[2][r] + accC[2][r] + bb[2], 0.0f);
            float w2 = fmaxf(accB[2][r] + accC[2][r] + bb[2], 0.0f);
            float v3 = fmaxf(accA[3][r] + accC[3][r] + bb[3], 0.0f);
            float w3 = fmaxf(accB[3][r] + accC[3][r] + bb[3], 0.0f);
            o.x = m * v0 + (1.0f - m) * w0;
            o.y = m * v1 + (1.0f - m) * w1;
            o.z = m * v2 + (1.0f - m) * w2;
            o.w = m * v3 + (1.0f - m) * w3;
            *(float4*)&xm2[(size_t)row * DH + colb] = o;
        }
        __syncthreads();
    }
}

// ================= logits + log_softmax, wave per row, 4 rows/block =================
__global__ __launch_bounds__(256) void logits_lsm(
        const float* __restrict__ xmix2, const float* __restrict__ Wlin,
        const float* __restrict__ blin, float* __restrict__ out, int nrows) {
    int w = threadIdx.x >> 6;
    int row = blockIdx.x * 4 + w;
    int t = threadIdx.x & 63;
    __shared__ float xs[4][DH];
    if (row < nrows)
        for (int i = t; i < DH; i += 64) xs[w][i] = xmix2[(size_t)row * DH + i];
    __syncthreads();
    if (row >= nrows) return;
    float acc = 0.0f;
    if (t < NC) {
        acc = blin[t];
        for (int k = 0; k < DH; k++) acc += xs[w][k] * Wlin[k * NC + t];
    }
    float v = (t < NC) ? acc : -INFINITY;
    float mx = v;
    for (int off = 32; off; off >>= 1) mx = fmaxf(mx, __shfl_xor(mx, off, 64));
    float ex = (t < NC) ? expf(acc - mx) : 0.0f;
    float sum = ex;
    for (int off = 32; off; off >>= 1) sum += __shfl_xor(sum, off, 64);
    if (t < NC) out[(size_t)row * NC + t] = acc - mx - logf(sum);
}

extern "C" void kernel_launch(void* const* d_in, const int* in_sizes, int n_in,
                              void* d_out, int out_size, void* d_ws, size_t ws_size,
                              hipStream_t stream) {
    const float* x0    = (const float*)d_in[0];
    const int*   src0  = (const int*)d_in[1];
    const int*   dst0  = (const int*)d_in[2];
    const int*   src1  = (const int*)d_in[3];
    const int*   dst1  = (const int*)d_in[4];
    const int*   srcb0 = (const int*)d_in[5];
    const int*   dstb0 = (const int*)d_in[6];
    const int*   srcb1 = (const int*)d_in[7];
    const int*   dstb1 = (const int*)d_in[8];
    const int*   idx   = (const int*)d_in[9];
    const float* mixp  = (const float*)d_in[10];
    const float* Wl0   = (const float*)d_in[11];
    const float* Wr0   = (const float*)d_in[12];
    const float* b0    = (const float*)d_in[13];
    const float* Wl1   = (const float*)d_in[14];
    const float* Wr1   = (const float*)d_in[15];
    const float* b1    = (const float*)d_in[16];
    const float* Wlin  = (const float*)d_in[17];
    const float* blin  = (const float*)d_in[18];
    float* out = (float*)d_out;

    const int E0 = in_sizes[1];
    const int E1 = in_sizes[3];
    const long x0elems = (long)in_sizes[0];

    // ---- workspace layout (8-replica buckets; xm1h trimmed to N2C rows) ----
    int* wsi    = (int*)d_ws;
    int* cur    = wsi;                                      // NREP*TOTCNT ints (3.2MB)
    int* bucket = cur + (size_t)NREP * TOTCNT;              // NREP*TOTCNT*CAPR (51.2MB)
    unsigned short* wsh = (unsigned short*)(bucket + (size_t)NREP * TOTCNT * CAPR);
    unsigned short* mean0  = wsh;                              // N1*128 bf16
    unsigned short* meanb0 = mean0  + (size_t)N1C * DIN;
    unsigned short* mean1  = meanb0 + (size_t)N1C * DIN;       // N2*256
    unsigned short* meanb1 = mean1  + (size_t)N2C * DH;
    unsigned short* xm1h   = meanb1 + (size_t)N2C * DH;        // N2*256 bf16 (trimmed)
    unsigned short* Wt0l   = xm1h   + (size_t)N2C * DH;
    unsigned short* Wt0r   = Wt0l + DIN * DH;
    unsigned short* Wt1l   = Wt0r + DIN * DH;
    unsigned short* Wt1r   = Wt1l + DH * DH;
    float* xm2 = (float*)(Wt1r + DH * DH);                     // N2*256 fp32
    unsigned char* x0f = (unsigned char*)(xm2 + (size_t)N2C * DH);  // N0*128 fp8
    unsigned char* x1f = x0f + (size_t)x0elems;                     // N1*256 fp8

    hipMemsetAsync(cur, 0, sizeof(int) * (size_t)NREP * TOTCNT, stream);

    // ---- fused front-end: thread-level {fill + conv} | weights in tail blocks ----
    int etot = 2 * E0 + 2 * E1;
    int n8 = (int)(x0elems / 8);
    int nbEdges = (etot + 255) / 256;
    int nbConv = (n8 + 255) / 256;
    int nbMain = nbEdges > nbConv ? nbEdges : nbConv;
    int nbW = (2 * DIN * DH + 2 * DH * DH + 255) / 256;
    front_fused<<<nbMain + nbW, 256, 0, stream>>>(
        src0, dst0, srcb0, dstb0, src1, dst1, srcb1, dstb1, idx, cur, bucket,
        E0, E1, nbMain, x0, x0f, n8,
        Wl0, Wr0, Wl1, Wr1, Wt0l, Wt0r, Wt1l, Wt1r);

    // ---- hop-0 aggregations (fp8 gather, LDS-merged replica lists) ----
    gather_mean_128f<<<2 * (N1C / 32), 256, 0, stream>>>(x0f, bucket, cur, mean0, meanb0);

    // ---- hop-0 MFMA ----
    hop0_mfma<<<N1C / (16 * H0T), 256, 0, stream>>>(x0, idx, mean0, meanb0, Wt0l, Wt0r,
                                                    b0, mixp, x1f, xm1h);

    // ---- hop-1 aggregations (fp8 gather, LDS-merged replica lists) ----
    gather_mean_256f<<<2 * (N2C / 16), 256, 0, stream>>>(x1f, bucket, cur, mean1, meanb1);

    // ---- hop-1 MFMA ----
    hop1_mfma<<<(N2C / 16 + H1T - 1) / H1T, 256, 0, stream>>>(mean1, meanb1, xm1h,
                                                              Wt1l, Wt1r, b1, mixp, xm2);

    // ---- logits + log_softmax ----
    logits_lsm<<<(N2C + 3) / 4, 256, 0, stream>>>(xm2, Wlin, blin, out, N2C);
}

// Round 11
// 322.098 us; speedup vs baseline: 1.0085x; 1.0085x over previous
//
#include <hip/hip_runtime.h>
#include <math.h>

// Problem constants (from reference)
#define N1C 40000
#define N2C 10000
#define DIN 128
#define DH  256
#define NC  47

#define TOTCNT (2 * N1C + 2 * N2C)          // 100000 concatenated bins
#define CAP 64                              // bucket capacity (P[deg>=65|lam=15] ~ 0)
#define NSLICE 8                            // bin-range slices (blockIdx&7 ~ XCD)
#define SLICEW (TOTCNT / NSLICE)            // 12500 bins per slice

typedef __attribute__((ext_vector_type(8))) short v8s;
typedef __attribute__((ext_vector_type(4))) float v4f;
typedef __attribute__((ext_vector_type(2))) float v2f;

#if __has_builtin(__builtin_amdgcn_cvt_pk_f32_fp8)
#define HW_FP8 1
#endif

__device__ __forceinline__ unsigned short f2bf(float f) {
    unsigned int u = __float_as_uint(f);
    u += 0x7FFF + ((u >> 16) & 1);            // round-to-nearest-even
    return (unsigned short)(u >> 16);
}

// ---- manual OCP e4m3fn encode (RNE, saturating) — fallback only ----
__device__ __forceinline__ unsigned char f2e4m3(float f) {
    unsigned int u = __float_as_uint(f);
    unsigned char s = (unsigned char)((u >> 24) & 0x80);
    float a = __uint_as_float(u & 0x7FFFFFFF);
    if (a > 448.0f) a = 448.0f;
    if (a < 0.015625f) {                       // subnorm / zero: quantum 2^-9
        int k = (int)rintf(a * 512.0f);        // 0..8 (8 rolls into e=1,m=0)
        return s | (unsigned char)k;
    }
    unsigned int bits = __float_as_uint(a);
    int et = (int)(bits >> 23) - 127 + 7;      // target exponent 1..15
    unsigned int m32 = bits & 0x7FFFFF;
    unsigned int m3 = m32 >> 20;
    unsigned int rest = m32 & 0xFFFFF;
    if (rest > 0x80000 || (rest == 0x80000 && (m3 & 1))) m3++;
    if (m3 == 8) { m3 = 0; et++; }
    if (et > 15 || (et == 15 && m3 == 7)) return s | 0x7E;   // clamp to 448
    return s | (unsigned char)((et << 3) | m3);
}

// pack 4 floats -> 4 e4m3 bytes (HW converter: r5/r6-verified)
__device__ __forceinline__ unsigned int pack4_e4m3(float f0, float f1,
                                                   float f2, float f3) {
#if __has_builtin(__builtin_amdgcn_cvt_pk_fp8_f32)
    int q = __builtin_amdgcn_cvt_pk_fp8_f32(f0, f1, 0, false);
    q = __builtin_amdgcn_cvt_pk_fp8_f32(f2, f3, q, true);
    return (unsigned int)q;
#else
    return (unsigned int)f2e4m3(f0) | ((unsigned int)f2e4m3(f1) << 8) |
           ((unsigned int)f2e4m3(f2) << 16) | ((unsigned int)f2e4m3(f3) << 24);
#endif
}

// decode 4 packed e4m3 bytes -> 4 floats
__device__ __forceinline__ void dec4(unsigned int u, float& f0, float& f1,
                                     float& f2, float& f3) {
#ifdef HW_FP8
    v2f lo = __builtin_amdgcn_cvt_pk_f32_fp8((int)u, false);
    v2f hi = __builtin_amdgcn_cvt_pk_f32_fp8((int)u, true);
    f0 = lo[0]; f1 = lo[1]; f2 = hi[0]; f3 = hi[1];
#else
    auto d1 = [](unsigned int b) -> float {
        int e = (b >> 3) & 15, mm = b & 7;
        float d = (e == 0) ? (float)mm * (1.0f / 512.0f)
                           : (1.0f + (float)mm * 0.125f) * exp2f((float)(e - 7));
        return (b & 0x80) ? -d : d;
    };
    f0 = d1(u & 0xFF); f1 = d1((u >> 8) & 0xFF);
    f2 = d1((u >> 16) & 0xFF); f3 = d1(u >> 24);
#endif
}

// accumulate 16 fp8 (one uint4) into 16 float accumulators
__device__ __forceinline__ void acc16(uint4 q, float* a) {
    float f0, f1, f2, f3;
    dec4(q.x, f0, f1, f2, f3); a[0] += f0; a[1] += f1; a[2] += f2; a[3] += f3;
    dec4(q.y, f0, f1, f2, f3); a[4] += f0; a[5] += f1; a[6] += f2; a[7] += f3;
    dec4(q.z, f0, f1, f2, f3); a[8] += f0; a[9] += f1; a[10] += f2; a[11] += f3;
    dec4(q.w, f0, f1, f2, f3); a[12] += f0; a[13] += f1; a[14] += f2; a[15] += f3;
}

// ====== fused front-end: SLICE-FILTERED fill + conv | weights in tail =============
// Each 2048-edge window is scanned by 8 blocks; block accepts only bins in its
// 12500-bin slice (slice = blockIdx&7 ~ XCD). Per-XCD dirty bucket working set
// drops 100K lines (6.4MB, thrash) -> 12.5K lines (~1MB, L2-resident) so scatter
// lines write back once instead of once PER EDGE (r10 analysis: WRITE_SIZE ~= 64B
// x 1.5M edges). dst arrays are read 8x (streaming, cheap); src/perm only for
// accepted edges.
__global__ __launch_bounds__(256) void front_fused(
        const int* __restrict__ src0, const int* __restrict__ dst0,
        const int* __restrict__ srcb0, const int* __restrict__ dstb0,
        const int* __restrict__ src1, const int* __restrict__ dst1,
        const int* __restrict__ srcb1, const int* __restrict__ dstb1,
        const int* __restrict__ perm, int* __restrict__ cur,
        int* __restrict__ bucket, int E0, int E1, int nbMain,
        const float* __restrict__ x0, unsigned char* __restrict__ x0f,
        int n8,
        const float* __restrict__ Wl0, const float* __restrict__ Wr0,
        const float* __restrict__ Wl1, const float* __restrict__ Wr1,
        unsigned short* __restrict__ Wt0l, unsigned short* __restrict__ Wt0r,
        unsigned short* __restrict__ Wt1l, unsigned short* __restrict__ Wt1r) {
    int b = blockIdx.x, t = threadIdx.x;
    if (b < nbMain) {
        int gid = b * 256 + t;
        // ---- conv: x0 -> fp8 (8 elems), independent stream ----
        if (gid < n8) {
            const float4* p = (const float4*)(x0 + (size_t)gid * 8);
            float4 a = p[0], c = p[1];
            uint2 q;
            q.x = pack4_e4m3(a.x, a.y, a.z, a.w);
            q.y = pack4_e4m3(c.x, c.y, c.z, c.w);
            *(uint2*)(x0f + (size_t)gid * 8) = q;
        }
        // ---- slice-filtered fill: 8 x 256-edge sub-windows ----
        int tot = 2 * E0 + 2 * E1;
        int binLo = (b & (NSLICE - 1)) * SLICEW;
        int wbase = (b >> 3) * 2048;
        if (wbase < tot) {
#pragma unroll
            for (int j = 0; j < 8; j++) {
                int e = wbase + j * 256 + t;
                if (e < tot) {
                    int bin;
                    if (e < E0)               bin = dst0[e];
                    else if (e < 2 * E0)      bin = N1C + dstb0[e - E0];
                    else if (e < 2 * E0 + E1) bin = 2 * N1C + dst1[e - 2 * E0];
                    else                      bin = 2 * N1C + N2C + dstb1[e - 2 * E0 - E1];
                    if ((unsigned)(bin - binLo) < (unsigned)SLICEW) {
                        int s;
                        if (e < E0)               s = src0[e];
                        else if (e < 2 * E0)      s = perm[srcb0[e - E0]];
                        else if (e < 2 * E0 + E1) s = src1[e - 2 * E0];
                        else                      s = perm[srcb1[e - 2 * E0 - E1]];
                        int pos = atomicAdd(&cur[bin], 1);
                        if (pos < CAP) bucket[(size_t)bin * CAP + pos] = s;
                    }
                }
            }
        }
    } else {
        // ---- weight transpose + bf16: Wt[n][k] = W[k][n] ----
        int id = (b - nbMain) * 256 + t;
        const int S0 = DIN * DH;   // 32768
        const int S1 = DH * DH;    // 65536
        const float* W; unsigned short* Wt; int K, loc;
        if (id < S0)                   { W = Wl0; Wt = Wt0l; K = DIN; loc = id; }
        else if (id < 2 * S0)          { W = Wr0; Wt = Wt0r; K = DIN; loc = id - S0; }
        else if (id < 2 * S0 + S1)     { W = Wl1; Wt = Wt1l; K = DH;  loc = id - 2 * S0; }
        else if (id < 2 * S0 + 2 * S1) { W = Wr1; Wt = Wt1r; K = DH;  loc = id - 2 * S0 - S1; }
        else return;
        int n = loc / K, k = loc - n * K;
        Wt[(size_t)n * K + k] = f2bf(W[(size_t)k * DH + n]);
    }
}

// ====== gather-mean D=128 (fp8): 8 rows/wave, 16B/lane (r9-verified form) =========
__global__ __launch_bounds__(256) void gather_mean_128f(
        const unsigned char* __restrict__ xf, const int* __restrict__ bucket,
        const int* __restrict__ cur, unsigned short* __restrict__ mean0,
        unsigned short* __restrict__ meanb0) {
    const int half = N1C / 32;                 // 1250 blocks per branch
    int b = blockIdx.x;
    int binbase; unsigned short* outp; int rb;
    if (b < half) { binbase = 0;   outp = mean0;  rb = b; }
    else          { binbase = N1C; outp = meanb0; rb = b - half; }
    int wv = threadIdx.x >> 6, lane = threadIdx.x & 63;
    int row = rb * 32 + wv * 8 + (lane >> 3);  // 4 waves x 8 rows = 32 rows/block
    int c16 = (lane & 7) * 16;                 // byte offset within 128B row
    int bin = binbase + row;
    int cnt = min(cur[bin], CAP);
    const int* cs = bucket + (size_t)bin * CAP;
    float a[16];
#pragma unroll
    for (int j = 0; j < 16; j++) a[j] = 0.0f;
    int i = 0;
    for (; i + 3 < cnt; i += 4) {
        int s0 = cs[i], s1 = cs[i + 1], s2 = cs[i + 2], s3 = cs[i + 3];
        uint4 q0 = *(const uint4*)&xf[(size_t)s0 * DIN + c16];
        uint4 q1 = *(const uint4*)&xf[(size_t)s1 * DIN + c16];
        uint4 q2 = *(const uint4*)&xf[(size_t)s2 * DIN + c16];
        uint4 q3 = *(const uint4*)&xf[(size_t)s3 * DIN + c16];
        acc16(q0, a); acc16(q1, a); acc16(q2, a); acc16(q3, a);
    }
    for (; i < cnt; i++) {
        uint4 q = *(const uint4*)&xf[(size_t)cs[i] * DIN + c16];
        acc16(q, a);
    }
    float inv = 1.0f / (float)max(cnt, 1);
    uint4 o0, o1;
    o0.x = (unsigned int)f2bf(a[0] * inv)  | ((unsigned int)f2bf(a[1] * inv) << 16);
    o0.y = (unsigned int)f2bf(a[2] * inv)  | ((unsigned int)f2bf(a[3] * inv) << 16);
    o0.z = (unsigned int)f2bf(a[4] * inv)  | ((unsigned int)f2bf(a[5] * inv) << 16);
    o0.w = (unsigned int)f2bf(a[6] * inv)  | ((unsigned int)f2bf(a[7] * inv) << 16);
    o1.x = (unsigned int)f2bf(a[8] * inv)  | ((unsigned int)f2bf(a[9] * inv) << 16);
    o1.y = (unsigned int)f2bf(a[10] * inv) | ((unsigned int)f2bf(a[11] * inv) << 16);
    o1.z = (unsigned int)f2bf(a[12] * inv) | ((unsigned int)f2bf(a[13] * inv) << 16);
    o1.w = (unsigned int)f2bf(a[14] * inv) | ((unsigned int)f2bf(a[15] * inv) << 16);
    unsigned short* op = &outp[(size_t)row * DIN + c16];
    *(uint4*)op = o0;
    *(uint4*)(op + 8) = o1;
}

// ====== gather-mean D=256 (fp8): 4 rows/wave, 16B/lane (r9-verified form) =========
__global__ __launch_bounds__(256) void gather_mean_256f(
        const unsigned char* __restrict__ xf, const int* __restrict__ bucket,
        const int* __restrict__ cur, unsigned short* __restrict__ mean1,
        unsigned short* __restrict__ meanb1) {
    const int half = N2C / 16;                 // 625 blocks per branch
    int b = blockIdx.x;
    int binbase; unsigned short* outp; int rb;
    if (b < half) { binbase = 2 * N1C;       outp = mean1;  rb = b; }
    else          { binbase = 2 * N1C + N2C; outp = meanb1; rb = b - half; }
    int wv = threadIdx.x >> 6, lane = threadIdx.x & 63;
    int row = rb * 16 + wv * 4 + (lane >> 4);  // 4 waves x 4 rows = 16 rows/block
    int c16 = (lane & 15) * 16;                // byte offset within 256B row
    int bin = binbase + row;
    int cnt = min(cur[bin], CAP);
    const int* cs = bucket + (size_t)bin * CAP;
    float a[16];
#pragma unroll
    for (int j = 0; j < 16; j++) a[j] = 0.0f;
    int i = 0;
    for (; i + 3 < cnt; i += 4) {
        int s0 = cs[i], s1 = cs[i + 1], s2 = cs[i + 2], s3 = cs[i + 3];
        uint4 q0 = *(const uint4*)&xf[(size_t)s0 * DH + c16];
        uint4 q1 = *(const uint4*)&xf[(size_t)s1 * DH + c16];
        uint4 q2 = *(const uint4*)&xf[(size_t)s2 * DH + c16];
        uint4 q3 = *(const uint4*)&xf[(size_t)s3 * DH + c16];
        acc16(q0, a); acc16(q1, a); acc16(q2, a); acc16(q3, a);
    }
    for (; i < cnt; i++) {
        uint4 q = *(const uint4*)&xf[(size_t)cs[i] * DH + c16];
        acc16(q, a);
    }
    float inv = 1.0f / (float)max(cnt, 1);
    uint4 o0, o1;
    o0.x = (unsigned int)f2bf(a[0] * inv)  | ((unsigned int)f2bf(a[1] * inv) << 16);
    o0.y = (unsigned int)f2bf(a[2] * inv)  | ((unsigned int)f2bf(a[3] * inv) << 16);
    o0.z = (unsigned int)f2bf(a[4] * inv)  | ((unsigned int)f2bf(a[5] * inv) << 16);
    o0.w = (unsigned int)f2bf(a[6] * inv)  | ((unsigned int)f2bf(a[7] * inv) << 16);
    o1.x = (unsigned int)f2bf(a[8] * inv)  | ((unsigned int)f2bf(a[9] * inv) << 16);
    o1.y = (unsigned int)f2bf(a[10] * inv) | ((unsigned int)f2bf(a[11] * inv) << 16);
    o1.z = (unsigned int)f2bf(a[12] * inv) | ((unsigned int)f2bf(a[13] * inv) << 16);
    o1.w = (unsigned int)f2bf(a[14] * inv) | ((unsigned int)f2bf(a[15] * inv) << 16);
    unsigned short* op = &outp[(size_t)row * DH + c16];
    *(uint4*)op = o0;
    *(uint4*)(op + 8) = o1;
}

// ================= hop-0 MFMA: weights in registers, 5 tiles/block =================
#define KP0 136  // 128 + 8 pad (bf16 units)
#define H0T 5    // grid = 40000/(16*5) = 500
__global__ __launch_bounds__(256, 2) void hop0_mfma(
        const float* __restrict__ x0, const int* __restrict__ idx,
        const unsigned short* __restrict__ mean0, const unsigned short* __restrict__ meanb0,
        const unsigned short* __restrict__ Wtl, const unsigned short* __restrict__ Wtr,
        const float* __restrict__ b, const float* __restrict__ mixp,
        unsigned char* __restrict__ x1f, unsigned short* __restrict__ xm1) {
    __shared__ unsigned short Alds[4][16][KP0];   // 0:mean 1:meanb 2:xr 3:xm
    int t = threadIdx.x;
    int wv = t >> 6, lane = t & 63;
    int mrow = lane & 15, quad = lane >> 4;
    float m = *mixp;

    v8s wl[4][4], wr[4][4];   // [ct][ks]
    float bb[4];
#pragma unroll
    for (int ct = 0; ct < 4; ct++) {
        int n = wv * 64 + mrow * 4 + ct;       // permuted column map
        bb[ct] = b[n];
#pragma unroll
        for (int ks = 0; ks < 4; ks++) {
            int k0 = ks * 32 + quad * 8;
            wl[ct][ks] = *(const v8s*)&Wtl[(size_t)n * DIN + k0];
            wr[ct][ks] = *(const v8s*)&Wtr[(size_t)n * DIN + k0];
        }
    }

    for (int tile = 0; tile < H0T; tile++) {
        int row0 = (blockIdx.x * H0T + tile) * 16;
        {   // stage A: roots read from fp32 x0 directly
            int r = t >> 4, k0 = (t & 15) * 8;
            int rg = row0 + r;
            *(v8s*)&Alds[0][r][k0] = *(const v8s*)&mean0[(size_t)rg * DIN + k0];
            *(v8s*)&Alds[1][r][k0] = *(const v8s*)&meanb0[(size_t)rg * DIN + k0];
            const float4* xr4 = (const float4*)&x0[(size_t)rg * DIN + k0];
            float4 A0 = xr4[0], A1 = xr4[1];
            int ib = idx[rg];
            const float4* xb4 = (const float4*)&x0[(size_t)ib * DIN + k0];
            float4 B0 = xb4[0], B1 = xb4[1];
            float fa[8] = {A0.x, A0.y, A0.z, A0.w, A1.x, A1.y, A1.z, A1.w};
            float fb[8] = {B0.x, B0.y, B0.z, B0.w, B1.x, B1.y, B1.z, B1.w};
            v8s vr, vm;
#pragma unroll
            for (int j = 0; j < 8; j++) {
                vr[j] = (short)f2bf(fa[j]);
                vm[j] = (short)f2bf(m * fa[j] + (1.0f - m) * fb[j]);
            }
            *(v8s*)&Alds[2][r][k0] = vr;
            *(v8s*)&Alds[3][r][k0] = vm;
        }
        __syncthreads();
        v4f accA[4], accB[4], accC[4], accD[4];
#pragma unroll
        for (int ct = 0; ct < 4; ct++) {
            accA[ct] = (v4f){0.f, 0.f, 0.f, 0.f}; accB[ct] = (v4f){0.f, 0.f, 0.f, 0.f};
            accC[ct] = (v4f){0.f, 0.f, 0.f, 0.f}; accD[ct] = (v4f){0.f, 0.f, 0.f, 0.f};
        }
#pragma unroll
        for (int ks = 0; ks < 4; ks++) {
            int k0 = ks * 32 + quad * 8;
            v8s aM = *(v8s*)&Alds[0][mrow][k0];
            v8s aB = *(v8s*)&Alds[1][mrow][k0];
            v8s aR = *(v8s*)&Alds[2][mrow][k0];
            v8s aX = *(v8s*)&Alds[3][mrow][k0];
#pragma unroll
            for (int ct = 0; ct < 4; ct++) {
                accA[ct] = __builtin_amdgcn_mfma_f32_16x16x32_bf16(aM, wl[ct][ks], accA[ct], 0, 0, 0);
                accB[ct] = __builtin_amdgcn_mfma_f32_16x16x32_bf16(aB, wl[ct][ks], accB[ct], 0, 0, 0);
                accC[ct] = __builtin_amdgcn_mfma_f32_16x16x32_bf16(aR, wr[ct][ks], accC[ct], 0, 0, 0);
                accD[ct] = __builtin_amdgcn_mfma_f32_16x16x32_bf16(aX, wr[ct][ks], accD[ct], 0, 0, 0);
            }
        }
        // epilogue: packed coalesced stores (4 consecutive cols per lane)
        int colb = wv * 64 + mrow * 4;
#pragma unroll
        for (int r = 0; r < 4; r++) {
            int row = row0 + quad * 4 + r;
            float xv[4];
            unsigned short sh[4];
#pragma unroll
            for (int ct = 0; ct < 4; ct++) {
                float pA = accA[ct][r], pB = accB[ct][r], pC = accC[ct][r], pD = accD[ct][r];
                xv[ct]    = fmaxf(pA + pC + bb[ct], 0.0f);
                float xn  = fmaxf(pA + pD + bb[ct], 0.0f);
                float xnb = fmaxf(pB + pD + bb[ct], 0.0f);
                sh[ct] = f2bf(m * xn + (1.0f - m) * xnb);
            }
            unsigned int xpack = pack4_e4m3(xv[0], xv[1], xv[2], xv[3]);
            *(unsigned int*)&x1f[(size_t)row * DH + colb] = xpack;
            if (row < N2C) {   // xm1 only consumed for rows < N2C (hop-1 roots)
                unsigned int s01 = (unsigned int)sh[0] | ((unsigned int)sh[1] << 16);
                unsigned int s23 = (unsigned int)sh[2] | ((unsigned int)sh[3] << 16);
                uint2 xm = {s01, s23};
                *(uint2*)&xm1[(size_t)row * DH + colb] = xm;
            }
        }
        __syncthreads();
    }
}

// ================= hop-1 MFMA: half-K weights cached, 2 tiles/block =================
#define KP1 264  // 256 + 8 pad
#define H1T 2
__global__ __launch_bounds__(256, 2) void hop1_mfma(
        const unsigned short* __restrict__ mean1, const unsigned short* __restrict__ meanb1,
        const unsigned short* __restrict__ xm1,
        const unsigned short* __restrict__ Wtl, const unsigned short* __restrict__ Wtr,
        const float* __restrict__ b, const float* __restrict__ mixp,
        float* __restrict__ xm2) {
    __shared__ unsigned short Alds[3][16][KP1];
    int t = threadIdx.x;
    int wv = t >> 6, lane = t & 63;
    int mrow = lane & 15, quad = lane >> 4;
    float m = *mixp;

    v8s wlc[4][4], wrc[4][4];
    float bb[4];
#pragma unroll
    for (int ct = 0; ct < 4; ct++) {
        int n = wv * 64 + mrow * 4 + ct;       // permuted column map
        bb[ct] = b[n];
#pragma unroll
        for (int ks = 0; ks < 4; ks++) {
            int k0 = ks * 32 + quad * 8;
            wlc[ct][ks] = *(const v8s*)&Wtl[(size_t)n * DH + k0];
            wrc[ct][ks] = *(const v8s*)&Wtr[(size_t)n * DH + k0];
        }
    }

    for (int tt = 0; tt < H1T; tt++) {
        int tIdx = blockIdx.x * H1T + tt;
        if (tIdx >= N2C / 16) break;
        int row0 = tIdx * 16;
        {
            int r = t >> 4, k0 = (t & 15) * 16;
            int rg = row0 + r;
            *(v8s*)&Alds[0][r][k0]     = *(const v8s*)&mean1[(size_t)rg * DH + k0];
            *(v8s*)&Alds[0][r][k0 + 8] = *(const v8s*)&mean1[(size_t)rg * DH + k0 + 8];
            *(v8s*)&Alds[1][r][k0]     = *(const v8s*)&meanb1[(size_t)rg * DH + k0];
            *(v8s*)&Alds[1][r][k0 + 8] = *(const v8s*)&meanb1[(size_t)rg * DH + k0 + 8];
            *(v8s*)&Alds[2][r][k0]     = *(const v8s*)&xm1[(size_t)rg * DH + k0];
            *(v8s*)&Alds[2][r][k0 + 8] = *(const v8s*)&xm1[(size_t)rg * DH + k0 + 8];
        }
        __syncthreads();
        v4f accA[4], accB[4], accC[4];
#pragma unroll
        for (int ct = 0; ct < 4; ct++) {
            accA[ct] = (v4f){0.f, 0.f, 0.f, 0.f};
            accB[ct] = (v4f){0.f, 0.f, 0.f, 0.f};
            accC[ct] = (v4f){0.f, 0.f, 0.f, 0.f};
        }
#pragma unroll
        for (int ks = 0; ks < 8; ks++) {
            int k0 = ks * 32 + quad * 8;
            v8s aM = *(v8s*)&Alds[0][mrow][k0];
            v8s aB = *(v8s*)&Alds[1][mrow][k0];
            v8s aR = *(v8s*)&Alds[2][mrow][k0];
#pragma unroll
            for (int ct = 0; ct < 4; ct++) {
                v8s bl, br;
                if (ks < 4) { bl = wlc[ct][ks]; br = wrc[ct][ks]; }
                else {
                    int n = wv * 64 + mrow * 4 + ct;
                    bl = *(const v8s*)&Wtl[(size_t)n * DH + k0];
                    br = *(const v8s*)&Wtr[(size_t)n * DH + k0];
                }
                accA[ct] = __builtin_amdgcn_mfma_f32_16x16x32_bf16(aM, bl, accA[ct], 0, 0, 0);
                accB[ct] = __builtin_amdgcn_mfma_f32_16x16x32_bf16(aB, bl, accB[ct], 0, 0, 0);
                accC[ct] = __builtin_amdgcn_mfma_f32_16x16x32_bf16(aR, br, accC[ct], 0, 0, 0);
            }
        }
        int colb = wv * 64 + mrow * 4;
#pragma unroll
        for (int r = 0; r < 4; r++) {
            int row = row0 + quad * 4 + r;
            float4 o;
            float v0 = fmaxf(accA[0][r] + accC[0][r] + bb[0], 0.0f);
            float w0 = fmaxf(accB[0][r] + accC[0][r] + bb[0], 0.0f);
            float v1 = fmaxf(accA[1][r] + accC[1][r] + bb[1], 0.0f);
            float w1 = fmaxf(accB[1][r] + accC[1][r] + bb[1], 0.0f);
            float v2 = fmaxf(accA[2][r] + accC[2][r] + bb[2], 0.0f);
            float w2 = fmaxf(accB[2][r] + accC[2][r] + bb[2], 0.0f);
            float v3 = fmaxf(accA[3][r] + accC[3][r] + bb[3], 0.0f);
            float w3 = fmaxf(accB[3][r] + accC[3][r] + bb[3], 0.0f);
            o.x = m * v0 + (1.0f - m) * w0;
            o.y = m * v1 + (1.0f - m) * w1;
            o.z = m * v2 + (1.0f - m) * w2;
            o.w = m * v3 + (1.0f - m) * w3;
            *(float4*)&xm2[(size_t)row * DH + colb] = o;
        }
        __syncthreads();
    }
}

// ================= logits + log_softmax, wave per row, 4 rows/block =================
__global__ __launch_bounds__(256) void logits_lsm(
        const float* __restrict__ xmix2, const float* __restrict__ Wlin,
        const float* __restrict__ blin, float* __restrict__ out, int nrows) {
    int w = threadIdx.x >> 6;
    int row = blockIdx.x * 4 + w;
    int t = threadIdx.x & 63;
    __shared__ float xs[4][DH];
    if (row < nrows)
        for (int i = t; i < DH; i += 64) xs[w][i] = xmix2[(size_t)row * DH + i];
    __syncthreads();
    if (row >= nrows) return;
    float acc = 0.0f;
    if (t < NC) {
        acc = blin[t];
        for (int k = 0; k < DH; k++) acc += xs[w][k] * Wlin[k * NC + t];
    }
    float v = (t < NC) ? acc : -INFINITY;
    float mx = v;
    for (int off = 32; off; off >>= 1) mx = fmaxf(mx, __shfl_xor(mx, off, 64));
    float ex = (t < NC) ? expf(acc - mx) : 0.0f;
    float sum = ex;
    for (int off = 32; off; off >>= 1) sum += __shfl_xor(sum, off, 64);
    if (t < NC) out[(size_t)row * NC + t] = acc - mx - logf(sum);
}

extern "C" void kernel_launch(void* const* d_in, const int* in_sizes, int n_in,
                              void* d_out, int out_size, void* d_ws, size_t ws_size,
                              hipStream_t stream) {
    const float* x0    = (const float*)d_in[0];
    const int*   src0  = (const int*)d_in[1];
    const int*   dst0  = (const int*)d_in[2];
    const int*   src1  = (const int*)d_in[3];
    const int*   dst1  = (const int*)d_in[4];
    const int*   srcb0 = (const int*)d_in[5];
    const int*   dstb0 = (const int*)d_in[6];
    const int*   srcb1 = (const int*)d_in[7];
    const int*   dstb1 = (const int*)d_in[8];
    const int*   idx   = (const int*)d_in[9];
    const float* mixp  = (const float*)d_in[10];
    const float* Wl0   = (const float*)d_in[11];
    const float* Wr0   = (const float*)d_in[12];
    const float* b0    = (const float*)d_in[13];
    const float* Wl1   = (const float*)d_in[14];
    const float* Wr1   = (const float*)d_in[15];
    const float* b1    = (const float*)d_in[16];
    const float* Wlin  = (const float*)d_in[17];
    const float* blin  = (const float*)d_in[18];
    float* out = (float*)d_out;

    const int E0 = in_sizes[1];
    const int E1 = in_sizes[3];
    const long x0elems = (long)in_sizes[0];

    // ---- workspace layout (dense counters; xm1h trimmed to N2C rows) ----
    int* wsi    = (int*)d_ws;
    int* cur    = wsi;                                      // TOTCNT ints (400KB)
    int* bucket = cur + TOTCNT;                             // TOTCNT*CAP (25.6MB)
    unsigned short* wsh = (unsigned short*)(bucket + (size_t)TOTCNT * CAP);
    unsigned short* mean0  = wsh;                              // N1*128 bf16
    unsigned short* meanb0 = mean0  + (size_t)N1C * DIN;
    unsigned short* mean1  = meanb0 + (size_t)N1C * DIN;       // N2*256
    unsigned short* meanb1 = mean1  + (size_t)N2C * DH;
    unsigned short* xm1h   = meanb1 + (size_t)N2C * DH;        // N2*256 bf16 (trimmed)
    unsigned short* Wt0l   = xm1h   + (size_t)N2C * DH;
    unsigned short* Wt0r   = Wt0l + DIN * DH;
    unsigned short* Wt1l   = Wt0r + DIN * DH;
    unsigned short* Wt1r   = Wt1l + DH * DH;
    float* xm2 = (float*)(Wt1r + DH * DH);                     // N2*256 fp32
    unsigned char* x0f = (unsigned char*)(xm2 + (size_t)N2C * DH);  // N0*128 fp8
    unsigned char* x1f = x0f + (size_t)x0elems;                     // N1*256 fp8

    hipMemsetAsync(cur, 0, sizeof(int) * (size_t)TOTCNT, stream);

    // ---- fused front-end: slice-filtered fill + conv | weights in tail blocks ----
    int etot = 2 * E0 + 2 * E1;
    int n8 = (int)(x0elems / 8);
    int nbFill = ((etot + 2047) / 2048) * NSLICE;
    int nbConv = (n8 + 255) / 256;
    int nbMain = nbFill > nbConv ? nbFill : nbConv;
    int nbW = (2 * DIN * DH + 2 * DH * DH + 255) / 256;
    front_fused<<<nbMain + nbW, 256, 0, stream>>>(
        src0, dst0, srcb0, dstb0, src1, dst1, srcb1, dstb1, idx, cur, bucket,
        E0, E1, nbMain, x0, x0f, n8,
        Wl0, Wr0, Wl1, Wr1, Wt0l, Wt0r, Wt1l, Wt1r);

    // ---- hop-0 aggregations (fp8 gather, 16B/lane) ----
    gather_mean_128f<<<2 * (N1C / 32), 256, 0, stream>>>(x0f, bucket, cur, mean0, meanb0);

    // ---- hop-0 MFMA ----
    hop0_mfma<<<N1C / (16 * H0T), 256, 0, stream>>>(x0, idx, mean0, meanb0, Wt0l, Wt0r,
                                                    b0, mixp, x1f, xm1h);

    // ---- hop-1 aggregations (fp8 gather, 16B/lane) ----
    gather_mean_256f<<<2 * (N2C / 16), 256, 0, stream>>>(x1f, bucket, cur, mean1, meanb1);

    // ---- hop-1 MFMA ----
    hop1_mfma<<<(N2C / 16 + H1T - 1) / H1T, 256, 0, stream>>>(mean1, meanb1, xm1h,
                                                              Wt1l, Wt1r, b1, mixp, xm2);

    // ---- logits + log_softmax ----
    logits_lsm<<<(N2C + 3) / 4, 256, 0, stream>>>(xm2, Wlin, blin, out, N2C);
}

// Round 12
// 314.244 us; speedup vs baseline: 1.0337x; 1.0250x over previous
//
#include <hip/hip_runtime.h>
#include <math.h>

// Problem constants (from reference)
#define N1C 40000
#define N2C 10000
#define DIN 128
#define DH  256
#define NC  47

#define TOTCNT (2 * N1C + 2 * N2C)          // 100000 concatenated bins
#define CAP 64                              // bucket capacity (P[deg>=65|lam=15] ~ 0)

typedef __attribute__((ext_vector_type(8))) short v8s;
typedef __attribute__((ext_vector_type(4))) float v4f;
typedef __attribute__((ext_vector_type(2))) float v2f;

#if __has_builtin(__builtin_amdgcn_cvt_pk_f32_fp8)
#define HW_FP8 1
#endif

__device__ __forceinline__ unsigned short f2bf(float f) {
    unsigned int u = __float_as_uint(f);
    u += 0x7FFF + ((u >> 16) & 1);            // round-to-nearest-even
    return (unsigned short)(u >> 16);
}

// ---- manual OCP e4m3fn encode (RNE, saturating) — fallback only ----
__device__ __forceinline__ unsigned char f2e4m3(float f) {
    unsigned int u = __float_as_uint(f);
    unsigned char s = (unsigned char)((u >> 24) & 0x80);
    float a = __uint_as_float(u & 0x7FFFFFFF);
    if (a > 448.0f) a = 448.0f;
    if (a < 0.015625f) {                       // subnorm / zero: quantum 2^-9
        int k = (int)rintf(a * 512.0f);        // 0..8 (8 rolls into e=1,m=0)
        return s | (unsigned char)k;
    }
    unsigned int bits = __float_as_uint(a);
    int et = (int)(bits >> 23) - 127 + 7;      // target exponent 1..15
    unsigned int m32 = bits & 0x7FFFFF;
    unsigned int m3 = m32 >> 20;
    unsigned int rest = m32 & 0xFFFFF;
    if (rest > 0x80000 || (rest == 0x80000 && (m3 & 1))) m3++;
    if (m3 == 8) { m3 = 0; et++; }
    if (et > 15 || (et == 15 && m3 == 7)) return s | 0x7E;   // clamp to 448
    return s | (unsigned char)((et << 3) | m3);
}

// pack 4 floats -> 4 e4m3 bytes (HW converter: r5/r6-verified)
__device__ __forceinline__ unsigned int pack4_e4m3(float f0, float f1,
                                                   float f2, float f3) {
#if __has_builtin(__builtin_amdgcn_cvt_pk_fp8_f32)
    int q = __builtin_amdgcn_cvt_pk_fp8_f32(f0, f1, 0, false);
    q = __builtin_amdgcn_cvt_pk_fp8_f32(f2, f3, q, true);
    return (unsigned int)q;
#else
    return (unsigned int)f2e4m3(f0) | ((unsigned int)f2e4m3(f1) << 8) |
           ((unsigned int)f2e4m3(f2) << 16) | ((unsigned int)f2e4m3(f3) << 24);
#endif
}

// decode 4 packed e4m3 bytes -> 4 floats
__device__ __forceinline__ void dec4(unsigned int u, float& f0, float& f1,
                                     float& f2, float& f3) {
#ifdef HW_FP8
    v2f lo = __builtin_amdgcn_cvt_pk_f32_fp8((int)u, false);
    v2f hi = __builtin_amdgcn_cvt_pk_f32_fp8((int)u, true);
    f0 = lo[0]; f1 = lo[1]; f2 = hi[0]; f3 = hi[1];
#else
    auto d1 = [](unsigned int b) -> float {
        int e = (b >> 3) & 15, mm = b & 7;
        float d = (e == 0) ? (float)mm * (1.0f / 512.0f)
                           : (1.0f + (float)mm * 0.125f) * exp2f((float)(e - 7));
        return (b & 0x80) ? -d : d;
    };
    f0 = d1(u & 0xFF); f1 = d1((u >> 8) & 0xFF);
    f2 = d1((u >> 16) & 0xFF); f3 = d1(u >> 24);
#endif
}

// accumulate 16 fp8 (one uint4) into 16 float accumulators
__device__ __forceinline__ void acc16(uint4 q, float* a) {
    float f0, f1, f2, f3;
    dec4(q.x, f0, f1, f2, f3); a[0] += f0; a[1] += f1; a[2] += f2; a[3] += f3;
    dec4(q.y, f0, f1, f2, f3); a[4] += f0; a[5] += f1; a[6] += f2; a[7] += f3;
    dec4(q.z, f0, f1, f2, f3); a[8] += f0; a[9] += f1; a[10] += f2; a[11] += f3;
    dec4(q.w, f0, f1, f2, f3); a[12] += f0; a[13] += f1; a[14] += f2; a[15] += f3;
}

// ====== fused front-end: thread-level {fill + conv} | weights in tail =============
// r8-verified structure (front ~= 85-91us; fill is memory-side atomic bound —
// r3/r4/r5/r10/r11 overlap/layout variants all land 84-118, r8 form is best-in-class
// simple). Dense counters (r10/r11-verified safe; counter-only lines don't hit r5's
// atomic+payload pathology).
__global__ __launch_bounds__(256) void front_fused(
        const int* __restrict__ src0, const int* __restrict__ dst0,
        const int* __restrict__ srcb0, const int* __restrict__ dstb0,
        const int* __restrict__ src1, const int* __restrict__ dst1,
        const int* __restrict__ srcb1, const int* __restrict__ dstb1,
        const int* __restrict__ perm, int* __restrict__ cur,
        int* __restrict__ bucket, int E0, int E1, int nbMain,
        const float* __restrict__ x0, unsigned char* __restrict__ x0f,
        int n8,
        const float* __restrict__ Wl0, const float* __restrict__ Wr0,
        const float* __restrict__ Wl1, const float* __restrict__ Wr1,
        unsigned short* __restrict__ Wt0l, unsigned short* __restrict__ Wt0r,
        unsigned short* __restrict__ Wt1l, unsigned short* __restrict__ Wt1r) {
    int b = blockIdx.x, t = threadIdx.x;
    if (b < nbMain) {
        int gid = b * 256 + t;
        // ---- fill: compute bin + issue atomic early ----
        int tot = 2 * E0 + 2 * E1;
        bool doEdge = gid < tot;
        int s = 0, bin = 0, pos = CAP;
        if (doEdge) {
            if (gid < E0) {
                s = src0[gid];                bin = dst0[gid];
            } else if (gid < 2 * E0) {
                int le = gid - E0;
                s = perm[srcb0[le]];          bin = N1C + dstb0[le];
            } else if (gid < 2 * E0 + E1) {
                int le = gid - 2 * E0;
                s = src1[le];                 bin = 2 * N1C + dst1[le];
            } else {
                int le = gid - 2 * E0 - E1;
                s = perm[srcb1[le]];          bin = 2 * N1C + N2C + dstb1[le];
            }
            pos = atomicAdd(&cur[bin], 1);
        }
        // ---- conv: x0 -> fp8 (8 elems), overlaps the atomic round-trip ----
        if (gid < n8) {
            const float4* p = (const float4*)(x0 + (size_t)gid * 8);
            float4 a = p[0], c = p[1];
            uint2 q;
            q.x = pack4_e4m3(a.x, a.y, a.z, a.w);
            q.y = pack4_e4m3(c.x, c.y, c.z, c.w);
            *(uint2*)(x0f + (size_t)gid * 8) = q;
        }
        // ---- dependent scatter last ----
        if (doEdge && pos < CAP) bucket[(size_t)bin * CAP + pos] = s;
    } else {
        // ---- weight transpose + bf16: Wt[n][k] = W[k][n] ----
        int id = (b - nbMain) * 256 + t;
        const int S0 = DIN * DH;   // 32768
        const int S1 = DH * DH;    // 65536
        const float* W; unsigned short* Wt; int K, loc;
        if (id < S0)                   { W = Wl0; Wt = Wt0l; K = DIN; loc = id; }
        else if (id < 2 * S0)          { W = Wr0; Wt = Wt0r; K = DIN; loc = id - S0; }
        else if (id < 2 * S0 + S1)     { W = Wl1; Wt = Wt1l; K = DH;  loc = id - 2 * S0; }
        else if (id < 2 * S0 + 2 * S1) { W = Wr1; Wt = Wt1r; K = DH;  loc = id - 2 * S0 - S1; }
        else return;
        int n = loc / K, k = loc - n * K;
        Wt[(size_t)n * K + k] = f2bf(W[(size_t)k * DH + n]);
    }
}

// ====== gather-mean D=128 (fp8): 8 rows/wave, 16B/lane (r9-verified, dense cur) ===
__global__ __launch_bounds__(256) void gather_mean_128f(
        const unsigned char* __restrict__ xf, const int* __restrict__ bucket,
        const int* __restrict__ cur, unsigned short* __restrict__ mean0,
        unsigned short* __restrict__ meanb0) {
    const int half = N1C / 32;                 // 1250 blocks per branch
    int b = blockIdx.x;
    int binbase; unsigned short* outp; int rb;
    if (b < half) { binbase = 0;   outp = mean0;  rb = b; }
    else          { binbase = N1C; outp = meanb0; rb = b - half; }
    int wv = threadIdx.x >> 6, lane = threadIdx.x & 63;
    int row = rb * 32 + wv * 8 + (lane >> 3);  // 4 waves x 8 rows = 32 rows/block
    int c16 = (lane & 7) * 16;                 // byte offset within 128B row
    int bin = binbase + row;
    int cnt = min(cur[bin], CAP);
    const int* cs = bucket + (size_t)bin * CAP;
    float a[16];
#pragma unroll
    for (int j = 0; j < 16; j++) a[j] = 0.0f;
    int i = 0;
    for (; i + 3 < cnt; i += 4) {
        int s0 = cs[i], s1 = cs[i + 1], s2 = cs[i + 2], s3 = cs[i + 3];
        uint4 q0 = *(const uint4*)&xf[(size_t)s0 * DIN + c16];
        uint4 q1 = *(const uint4*)&xf[(size_t)s1 * DIN + c16];
        uint4 q2 = *(const uint4*)&xf[(size_t)s2 * DIN + c16];
        uint4 q3 = *(const uint4*)&xf[(size_t)s3 * DIN + c16];
        acc16(q0, a); acc16(q1, a); acc16(q2, a); acc16(q3, a);
    }
    for (; i < cnt; i++) {
        uint4 q = *(const uint4*)&xf[(size_t)cs[i] * DIN + c16];
        acc16(q, a);
    }
    float inv = 1.0f / (float)max(cnt, 1);
    uint4 o0, o1;
    o0.x = (unsigned int)f2bf(a[0] * inv)  | ((unsigned int)f2bf(a[1] * inv) << 16);
    o0.y = (unsigned int)f2bf(a[2] * inv)  | ((unsigned int)f2bf(a[3] * inv) << 16);
    o0.z = (unsigned int)f2bf(a[4] * inv)  | ((unsigned int)f2bf(a[5] * inv) << 16);
    o0.w = (unsigned int)f2bf(a[6] * inv)  | ((unsigned int)f2bf(a[7] * inv) << 16);
    o1.x = (unsigned int)f2bf(a[8] * inv)  | ((unsigned int)f2bf(a[9] * inv) << 16);
    o1.y = (unsigned int)f2bf(a[10] * inv) | ((unsigned int)f2bf(a[11] * inv) << 16);
    o1.z = (unsigned int)f2bf(a[12] * inv) | ((unsigned int)f2bf(a[13] * inv) << 16);
    o1.w = (unsigned int)f2bf(a[14] * inv) | ((unsigned int)f2bf(a[15] * inv) << 16);
    unsigned short* op = &outp[(size_t)row * DIN + c16];
    *(uint4*)op = o0;
    *(uint4*)(op + 8) = o1;
}

// ====== gather-mean D=256 (fp8): 4 rows/wave, 16B/lane (r9-verified, dense cur) ===
__global__ __launch_bounds__(256) void gather_mean_256f(
        const unsigned char* __restrict__ xf, const int* __restrict__ bucket,
        const int* __restrict__ cur, unsigned short* __restrict__ mean1,
        unsigned short* __restrict__ meanb1) {
    const int half = N2C / 16;                 // 625 blocks per branch
    int b = blockIdx.x;
    int binbase; unsigned short* outp; int rb;
    if (b < half) { binbase = 2 * N1C;       outp = mean1;  rb = b; }
    else          { binbase = 2 * N1C + N2C; outp = meanb1; rb = b - half; }
    int wv = threadIdx.x >> 6, lane = threadIdx.x & 63;
    int row = rb * 16 + wv * 4 + (lane >> 4);  // 4 waves x 4 rows = 16 rows/block
    int c16 = (lane & 15) * 16;                // byte offset within 256B row
    int bin = binbase + row;
    int cnt = min(cur[bin], CAP);
    const int* cs = bucket + (size_t)bin * CAP;
    float a[16];
#pragma unroll
    for (int j = 0; j < 16; j++) a[j] = 0.0f;
    int i = 0;
    for (; i + 3 < cnt; i += 4) {
        int s0 = cs[i], s1 = cs[i + 1], s2 = cs[i + 2], s3 = cs[i + 3];
        uint4 q0 = *(const uint4*)&xf[(size_t)s0 * DH + c16];
        uint4 q1 = *(const uint4*)&xf[(size_t)s1 * DH + c16];
        uint4 q2 = *(const uint4*)&xf[(size_t)s2 * DH + c16];
        uint4 q3 = *(const uint4*)&xf[(size_t)s3 * DH + c16];
        acc16(q0, a); acc16(q1, a); acc16(q2, a); acc16(q3, a);
    }
    for (; i < cnt; i++) {
        uint4 q = *(const uint4*)&xf[(size_t)cs[i] * DH + c16];
        acc16(q, a);
    }
    float inv = 1.0f / (float)max(cnt, 1);
    uint4 o0, o1;
    o0.x = (unsigned int)f2bf(a[0] * inv)  | ((unsigned int)f2bf(a[1] * inv) << 16);
    o0.y = (unsigned int)f2bf(a[2] * inv)  | ((unsigned int)f2bf(a[3] * inv) << 16);
    o0.z = (unsigned int)f2bf(a[4] * inv)  | ((unsigned int)f2bf(a[5] * inv) << 16);
    o0.w = (unsigned int)f2bf(a[6] * inv)  | ((unsigned int)f2bf(a[7] * inv) << 16);
    o1.x = (unsigned int)f2bf(a[8] * inv)  | ((unsigned int)f2bf(a[9] * inv) << 16);
    o1.y = (unsigned int)f2bf(a[10] * inv) | ((unsigned int)f2bf(a[11] * inv) << 16);
    o1.z = (unsigned int)f2bf(a[12] * inv) | ((unsigned int)f2bf(a[13] * inv) << 16);
    o1.w = (unsigned int)f2bf(a[14] * inv) | ((unsigned int)f2bf(a[15] * inv) << 16);
    unsigned short* op = &outp[(size_t)row * DH + c16];
    *(uint4*)op = o0;
    *(uint4*)(op + 8) = o1;
}

// ================= hop-0 MFMA: weights in registers, 5 tiles/block =================
#define KP0 136  // 128 + 8 pad (bf16 units)
#define H0T 5    // grid = 40000/(16*5) = 500
__global__ __launch_bounds__(256, 2) void hop0_mfma(
        const float* __restrict__ x0, const int* __restrict__ idx,
        const unsigned short* __restrict__ mean0, const unsigned short* __restrict__ meanb0,
        const unsigned short* __restrict__ Wtl, const unsigned short* __restrict__ Wtr,
        const float* __restrict__ b, const float* __restrict__ mixp,
        unsigned char* __restrict__ x1f, unsigned short* __restrict__ xm1) {
    __shared__ unsigned short Alds[4][16][KP0];   // 0:mean 1:meanb 2:xr 3:xm
    int t = threadIdx.x;
    int wv = t >> 6, lane = t & 63;
    int mrow = lane & 15, quad = lane >> 4;
    float m = *mixp;

    v8s wl[4][4], wr[4][4];   // [ct][ks]
    float bb[4];
#pragma unroll
    for (int ct = 0; ct < 4; ct++) {
        int n = wv * 64 + mrow * 4 + ct;       // permuted column map
        bb[ct] = b[n];
#pragma unroll
        for (int ks = 0; ks < 4; ks++) {
            int k0 = ks * 32 + quad * 8;
            wl[ct][ks] = *(const v8s*)&Wtl[(size_t)n * DIN + k0];
            wr[ct][ks] = *(const v8s*)&Wtr[(size_t)n * DIN + k0];
        }
    }

    for (int tile = 0; tile < H0T; tile++) {
        int row0 = (blockIdx.x * H0T + tile) * 16;
        {   // stage A: roots read from fp32 x0 directly
            int r = t >> 4, k0 = (t & 15) * 8;
            int rg = row0 + r;
            *(v8s*)&Alds[0][r][k0] = *(const v8s*)&mean0[(size_t)rg * DIN + k0];
            *(v8s*)&Alds[1][r][k0] = *(const v8s*)&meanb0[(size_t)rg * DIN + k0];
            const float4* xr4 = (const float4*)&x0[(size_t)rg * DIN + k0];
            float4 A0 = xr4[0], A1 = xr4[1];
            int ib = idx[rg];
            const float4* xb4 = (const float4*)&x0[(size_t)ib * DIN + k0];
            float4 B0 = xb4[0], B1 = xb4[1];
            float fa[8] = {A0.x, A0.y, A0.z, A0.w, A1.x, A1.y, A1.z, A1.w};
            float fb[8] = {B0.x, B0.y, B0.z, B0.w, B1.x, B1.y, B1.z, B1.w};
            v8s vr, vm;
#pragma unroll
            for (int j = 0; j < 8; j++) {
                vr[j] = (short)f2bf(fa[j]);
                vm[j] = (short)f2bf(m * fa[j] + (1.0f - m) * fb[j]);
            }
            *(v8s*)&Alds[2][r][k0] = vr;
            *(v8s*)&Alds[3][r][k0] = vm;
        }
        __syncthreads();
        v4f accA[4], accB[4], accC[4], accD[4];
#pragma unroll
        for (int ct = 0; ct < 4; ct++) {
            accA[ct] = (v4f){0.f, 0.f, 0.f, 0.f}; accB[ct] = (v4f){0.f, 0.f, 0.f, 0.f};
            accC[ct] = (v4f){0.f, 0.f, 0.f, 0.f}; accD[ct] = (v4f){0.f, 0.f, 0.f, 0.f};
        }
#pragma unroll
        for (int ks = 0; ks < 4; ks++) {
            int k0 = ks * 32 + quad * 8;
            v8s aM = *(v8s*)&Alds[0][mrow][k0];
            v8s aB = *(v8s*)&Alds[1][mrow][k0];
            v8s aR = *(v8s*)&Alds[2][mrow][k0];
            v8s aX = *(v8s*)&Alds[3][mrow][k0];
#pragma unroll
            for (int ct = 0; ct < 4; ct++) {
                accA[ct] = __builtin_amdgcn_mfma_f32_16x16x32_bf16(aM, wl[ct][ks], accA[ct], 0, 0, 0);
                accB[ct] = __builtin_amdgcn_mfma_f32_16x16x32_bf16(aB, wl[ct][ks], accB[ct], 0, 0, 0);
                accC[ct] = __builtin_amdgcn_mfma_f32_16x16x32_bf16(aR, wr[ct][ks], accC[ct], 0, 0, 0);
                accD[ct] = __builtin_amdgcn_mfma_f32_16x16x32_bf16(aX, wr[ct][ks], accD[ct], 0, 0, 0);
            }
        }
        // epilogue: packed coalesced stores (4 consecutive cols per lane)
        int colb = wv * 64 + mrow * 4;
#pragma unroll
        for (int r = 0; r < 4; r++) {
            int row = row0 + quad * 4 + r;
            float xv[4];
            unsigned short sh[4];
#pragma unroll
            for (int ct = 0; ct < 4; ct++) {
                float pA = accA[ct][r], pB = accB[ct][r], pC = accC[ct][r], pD = accD[ct][r];
                xv[ct]    = fmaxf(pA + pC + bb[ct], 0.0f);
                float xn  = fmaxf(pA + pD + bb[ct], 0.0f);
                float xnb = fmaxf(pB + pD + bb[ct], 0.0f);
                sh[ct] = f2bf(m * xn + (1.0f - m) * xnb);
            }
            unsigned int xpack = pack4_e4m3(xv[0], xv[1], xv[2], xv[3]);
            *(unsigned int*)&x1f[(size_t)row * DH + colb] = xpack;
            if (row < N2C) {   // xm1 only consumed for rows < N2C (hop-1 roots)
                unsigned int s01 = (unsigned int)sh[0] | ((unsigned int)sh[1] << 16);
                unsigned int s23 = (unsigned int)sh[2] | ((unsigned int)sh[3] << 16);
                uint2 xm = {s01, s23};
                *(uint2*)&xm1[(size_t)row * DH + colb] = xm;
            }
        }
        __syncthreads();
    }
}

// ================= hop-1 MFMA: half-K weights cached, 2 tiles/block =================
#define KP1 264  // 256 + 8 pad
#define H1T 2
__global__ __launch_bounds__(256, 2) void hop1_mfma(
        const unsigned short* __restrict__ mean1, const unsigned short* __restrict__ meanb1,
        const unsigned short* __restrict__ xm1,
        const unsigned short* __restrict__ Wtl, const unsigned short* __restrict__ Wtr,
        const float* __restrict__ b, const float* __restrict__ mixp,
        float* __restrict__ xm2) {
    __shared__ unsigned short Alds[3][16][KP1];
    int t = threadIdx.x;
    int wv = t >> 6, lane = t & 63;
    int mrow = lane & 15, quad = lane >> 4;
    float m = *mixp;

    v8s wlc[4][4], wrc[4][4];
    float bb[4];
#pragma unroll
    for (int ct = 0; ct < 4; ct++) {
        int n = wv * 64 + mrow * 4 + ct;       // permuted column map
        bb[ct] = b[n];
#pragma unroll
        for (int ks = 0; ks < 4; ks++) {
            int k0 = ks * 32 + quad * 8;
            wlc[ct][ks] = *(const v8s*)&Wtl[(size_t)n * DH + k0];
            wrc[ct][ks] = *(const v8s*)&Wtr[(size_t)n * DH + k0];
        }
    }

    for (int tt = 0; tt < H1T; tt++) {
        int tIdx = blockIdx.x * H1T + tt;
        if (tIdx >= N2C / 16) break;
        int row0 = tIdx * 16;
        {
            int r = t >> 4, k0 = (t & 15) * 16;
            int rg = row0 + r;
            *(v8s*)&Alds[0][r][k0]     = *(const v8s*)&mean1[(size_t)rg * DH + k0];
            *(v8s*)&Alds[0][r][k0 + 8] = *(const v8s*)&mean1[(size_t)rg * DH + k0 + 8];
            *(v8s*)&Alds[1][r][k0]     = *(const v8s*)&meanb1[(size_t)rg * DH + k0];
            *(v8s*)&Alds[1][r][k0 + 8] = *(const v8s*)&meanb1[(size_t)rg * DH + k0 + 8];
            *(v8s*)&Alds[2][r][k0]     = *(const v8s*)&xm1[(size_t)rg * DH + k0];
            *(v8s*)&Alds[2][r][k0 + 8] = *(const v8s*)&xm1[(size_t)rg * DH + k0 + 8];
        }
        __syncthreads();
        v4f accA[4], accB[4], accC[4];
#pragma unroll
        for (int ct = 0; ct < 4; ct++) {
            accA[ct] = (v4f){0.f, 0.f, 0.f, 0.f};
            accB[ct] = (v4f){0.f, 0.f, 0.f, 0.f};
            accC[ct] = (v4f){0.f, 0.f, 0.f, 0.f};
        }
#pragma unroll
        for (int ks = 0; ks < 8; ks++) {
            int k0 = ks * 32 + quad * 8;
            v8s aM = *(v8s*)&Alds[0][mrow][k0];
            v8s aB = *(v8s*)&Alds[1][mrow][k0];
            v8s aR = *(v8s*)&Alds[2][mrow][k0];
#pragma unroll
            for (int ct = 0; ct < 4; ct++) {
                v8s bl, br;
                if (ks < 4) { bl = wlc[ct][ks]; br = wrc[ct][ks]; }
                else {
                    int n = wv * 64 + mrow * 4 + ct;
                    bl = *(const v8s*)&Wtl[(size_t)n * DH + k0];
                    br = *(const v8s*)&Wtr[(size_t)n * DH + k0];
                }
                accA[ct] = __builtin_amdgcn_mfma_f32_16x16x32_bf16(aM, bl, accA[ct], 0, 0, 0);
                accB[ct] = __builtin_amdgcn_mfma_f32_16x16x32_bf16(aB, bl, accB[ct], 0, 0, 0);
                accC[ct] = __builtin_amdgcn_mfma_f32_16x16x32_bf16(aR, br, accC[ct], 0, 0, 0);
            }
        }
        int colb = wv * 64 + mrow * 4;
#pragma unroll
        for (int r = 0; r < 4; r++) {
            int row = row0 + quad * 4 + r;
            float4 o;
            float v0 = fmaxf(accA[0][r] + accC[0][r] + bb[0], 0.0f);
            float w0 = fmaxf(accB[0][r] + accC[0][r] + bb[0], 0.0f);
            float v1 = fmaxf(accA[1][r] + accC[1][r] + bb[1], 0.0f);
            float w1 = fmaxf(accB[1][r] + accC[1][r] + bb[1], 0.0f);
            float v2 = fmaxf(accA[2][r] + accC[2][r] + bb[2], 0.0f);
            float w2 = fmaxf(accB[2][r] + accC[2][r] + bb[2], 0.0f);
            float v3 = fmaxf(accA[3][r] + accC[3][r] + bb[3], 0.0f);
            float w3 = fmaxf(accB[3][r] + accC[3][r] + bb[3], 0.0f);
            o.x = m * v0 + (1.0f - m) * w0;
            o.y = m * v1 + (1.0f - m) * w1;
            o.z = m * v2 + (1.0f - m) * w2;
            o.w = m * v3 + (1.0f - m) * w3;
            *(float4*)&xm2[(size_t)row * DH + colb] = o;
        }
        __syncthreads();
    }
}

// ================= logits + log_softmax, wave per row, 4 rows/block =================
__global__ __launch_bounds__(256) void logits_lsm(
        const float* __restrict__ xmix2, const float* __restrict__ Wlin,
        const float* __restrict__ blin, float* __restrict__ out, int nrows) {
    int w = threadIdx.x >> 6;
    int row = blockIdx.x * 4 + w;
    int t = threadIdx.x & 63;
    __shared__ float xs[4][DH];
    if (row < nrows)
        for (int i = t; i < DH; i += 64) xs[w][i] = xmix2[(size_t)row * DH + i];
    __syncthreads();
    if (row >= nrows) return;
    float acc = 0.0f;
    if (t < NC) {
        acc = blin[t];
        for (int k = 0; k < DH; k++) acc += xs[w][k] * Wlin[k * NC + t];
    }
    float v = (t < NC) ? acc : -INFINITY;
    float mx = v;
    for (int off = 32; off; off >>= 1) mx = fmaxf(mx, __shfl_xor(mx, off, 64));
    float ex = (t < NC) ? expf(acc - mx) : 0.0f;
    float sum = ex;
    for (int off = 32; off; off >>= 1) sum += __shfl_xor(sum, off, 64);
    if (t < NC) out[(size_t)row * NC + t] = acc - mx - logf(sum);
}

extern "C" void kernel_launch(void* const* d_in, const int* in_sizes, int n_in,
                              void* d_out, int out_size, void* d_ws, size_t ws_size,
                              hipStream_t stream) {
    const float* x0    = (const float*)d_in[0];
    const int*   src0  = (const int*)d_in[1];
    const int*   dst0  = (const int*)d_in[2];
    const int*   src1  = (const int*)d_in[3];
    const int*   dst1  = (const int*)d_in[4];
    const int*   srcb0 = (const int*)d_in[5];
    const int*   dstb0 = (const int*)d_in[6];
    const int*   srcb1 = (const int*)d_in[7];
    const int*   dstb1 = (const int*)d_in[8];
    const int*   idx   = (const int*)d_in[9];
    const float* mixp  = (const float*)d_in[10];
    const float* Wl0   = (const float*)d_in[11];
    const float* Wr0   = (const float*)d_in[12];
    const float* b0    = (const float*)d_in[13];
    const float* Wl1   = (const float*)d_in[14];
    const float* Wr1   = (const float*)d_in[15];
    const float* b1    = (const float*)d_in[16];
    const float* Wlin  = (const float*)d_in[17];
    const float* blin  = (const float*)d_in[18];
    float* out = (float*)d_out;

    const int E0 = in_sizes[1];
    const int E1 = in_sizes[3];
    const long x0elems = (long)in_sizes[0];

    // ---- workspace layout (dense counters; xm1h trimmed to N2C rows) ----
    int* wsi    = (int*)d_ws;
    int* cur    = wsi;                                      // TOTCNT ints (400KB)
    int* bucket = cur + TOTCNT;                             // TOTCNT*CAP (25.6MB)
    unsigned short* wsh = (unsigned short*)(bucket + (size_t)TOTCNT * CAP);
    unsigned short* mean0  = wsh;                              // N1*128 bf16
    unsigned short* meanb0 = mean0  + (size_t)N1C * DIN;
    unsigned short* mean1  = meanb0 + (size_t)N1C * DIN;       // N2*256
    unsigned short* meanb1 = mean1  + (size_t)N2C * DH;
    unsigned short* xm1h   = meanb1 + (size_t)N2C * DH;        // N2*256 bf16 (trimmed)
    unsigned short* Wt0l   = xm1h   + (size_t)N2C * DH;
    unsigned short* Wt0r   = Wt0l + DIN * DH;
    unsigned short* Wt1l   = Wt0r + DIN * DH;
    unsigned short* Wt1r   = Wt1l + DH * DH;
    float* xm2 = (float*)(Wt1r + DH * DH);                     // N2*256 fp32
    unsigned char* x0f = (unsigned char*)(xm2 + (size_t)N2C * DH);  // N0*128 fp8
    unsigned char* x1f = x0f + (size_t)x0elems;                     // N1*256 fp8

    hipMemsetAsync(cur, 0, sizeof(int) * (size_t)TOTCNT, stream);

    // ---- fused front-end: thread-level {fill + conv} | weights in tail blocks ----
    int etot = 2 * E0 + 2 * E1;
    int n8 = (int)(x0elems / 8);
    int nbEdges = (etot + 255) / 256;
    int nbConv = (n8 + 255) / 256;
    int nbMain = nbEdges > nbConv ? nbEdges : nbConv;
    int nbW = (2 * DIN * DH + 2 * DH * DH + 255) / 256;
    front_fused<<<nbMain + nbW, 256, 0, stream>>>(
        src0, dst0, srcb0, dstb0, src1, dst1, srcb1, dstb1, idx, cur, bucket,
        E0, E1, nbMain, x0, x0f, n8,
        Wl0, Wr0, Wl1, Wr1, Wt0l, Wt0r, Wt1l, Wt1r);

    // ---- hop-0 aggregations (fp8 gather, 16B/lane) ----
    gather_mean_128f<<<2 * (N1C / 32), 256, 0, stream>>>(x0f, bucket, cur, mean0, meanb0);

    // ---- hop-0 MFMA ----
    hop0_mfma<<<N1C / (16 * H0T), 256, 0, stream>>>(x0, idx, mean0, meanb0, Wt0l, Wt0r,
                                                    b0, mixp, x1f, xm1h);

    // ---- hop-1 aggregations (fp8 gather, 16B/lane) ----
    gather_mean_256f<<<2 * (N2C / 16), 256, 0, stream>>>(x1f, bucket, cur, mean1, meanb1);

    // ---- hop-1 MFMA ----
    hop1_mfma<<<(N2C / 16 + H1T - 1) / H1T, 256, 0, stream>>>(mean1, meanb1, xm1h,
                                                              Wt1l, Wt1r, b1, mixp, xm2);

    // ---- logits + log_softmax ----
    logits_lsm<<<(N2C + 3) / 4, 256, 0, stream>>>(xm2, Wlin, blin, out, N2C);
}